// Round 11
// baseline (1235.478 us; speedup 1.0000x reference)
//
#include <hip/hip_runtime.h>

#define TT 2048
#define HH 64
#define II 6
#define OO 6
#define NTHR 512   // 8 waves: 4 A-waves (layer0 + Wih1@h0), 4 B-waves (layer1 + FC)

typedef float    f32x4 __attribute__((ext_vector_type(4)));
typedef float    f32x2 __attribute__((ext_vector_type(2)));
typedef _Float16 f16x8 __attribute__((ext_vector_type(8)));

__device__ __forceinline__ float fast_sig(float v) {
    return __builtin_amdgcn_rcpf(1.0f + __expf(-v));
}
__device__ __forceinline__ float fast_tanh(float v) {
    return 1.0f - 2.0f * __builtin_amdgcn_rcpf(__expf(2.0f * v) + 1.0f);
}

#define MFMA(a, b, c) __builtin_amdgcn_mfma_f32_16x16x32_f16((a), (b), (c), 0, 0, 0)

// LDS-only barrier: do NOT drain vmcnt (global x-prefetch / out-stores stay in
// flight across the barrier; their results are register-awaited at use).
#define LGKM_BARRIER() asm volatile("s_waitcnt lgkmcnt(0)\ns_barrier" ::: "memory")

__global__
__attribute__((amdgpu_flat_work_group_size(NTHR, NTHR)))
__attribute__((amdgpu_waves_per_eu(2, 2)))
void lstm_mfma_kernel(const float* __restrict__ x,
                      const float* __restrict__ Wih0, const float* __restrict__ Whh0,
                      const float* __restrict__ b0,
                      const float* __restrict__ Wih1, const float* __restrict__ Whh1,
                      const float* __restrict__ b1,
                      const float* __restrict__ W1, const float* __restrict__ bf1,
                      const float* __restrict__ W2, const float* __restrict__ bf2,
                      float* __restrict__ out)
{
    const int row  = blockIdx.x;      // one batch row per block
    const int tid  = threadIdx.x;
    const int wid  = tid >> 6;        // wave id 0..7
    const int lane = tid & 63;
    const int n    = lane & 15;       // MFMA col-lane (B-col / D-col)
    const int q    = lane >> 4;       // k-group: lane holds k = 8q..8q+7 (+32 for a1)
    const bool isA = wid < 4;
    const int  w   = isA ? wid : wid - 4;   // role-local wave index 0..3

    // Only the REAL row (D/A row 0) is stored; all 16 A-rows get identical data
    // (broadcast). Garbage rows 1-15 of D are discarded.
    __shared__ __attribute__((aligned(16))) _Float16 H0[2][HH];
    __shared__ __attribute__((aligned(16))) _Float16 H1[2][HH];
    __shared__ __attribute__((aligned(16))) _Float16 Rb[2][HH];
    __shared__ __attribute__((aligned(16))) float    XG[2][256]; // xg1 strip (f32)

    if (tid < HH) {
        H0[0][tid] = (_Float16)0.f; H0[1][tid] = (_Float16)0.f;
        H1[0][tid] = (_Float16)0.f; H1[1][tid] = (_Float16)0.f;
        Rb[0][tid] = (_Float16)0.f; Rb[1][tid] = (_Float16)0.f;
    }
    if (tid < 256) { XG[0][tid] = 0.f; XG[1][tid] = 0.f; }

    // ---- build weight B-frags (once). Same k->elem map as the A-frag reads
    // (elem i <-> k = kbase + 8q + i), so the mapping cancels inside the dot.
    f16x8 frag[20];
    float bias[8];
    #pragma unroll
    for (int i = 0; i < 8; ++i) bias[i] = 0.f;

    auto mk = [&](const float* W, int r, int ld, int kbase, int kmax, bool rok) {
        f16x8 f;
        #pragma unroll
        for (int i = 0; i < 8; ++i) {
            int kk = kbase + 8 * q + i;
            f[i] = (rok && kk < kmax) ? (_Float16)W[r * ld + kk] : (_Float16)0.f;
        }
        return f;
    };

    if (isA) {
        #pragma unroll
        for (int g = 0; g < 4; ++g) {
            const int r0 = g * HH + 16 * w + n;        // gate row (i,f,g,o stacked)
            frag[g * 3 + 0] = mk(Whh0, r0, HH, 0,  HH, true);
            frag[g * 3 + 1] = mk(Whh0, r0, HH, 32, HH, true);
            frag[g * 3 + 2] = mk(Wih0, r0, II, 0,  II, true);   // x-chunk (k>=6 zero)
            bias[g] = b0[r0];
            const int r1 = 16 * (4 * g + w) + n;       // xg1 output index
            frag[12 + g * 2 + 0] = mk(Wih1, r1, HH, 0,  HH, true);
            frag[12 + g * 2 + 1] = mk(Wih1, r1, HH, 32, HH, true);
            bias[4 + g] = b1[r1];
        }
    } else {
        #pragma unroll
        for (int g = 0; g < 4; ++g) {
            const int r0 = g * HH + 16 * w + n;
            frag[g * 2 + 0] = mk(Whh1, r0, HH, 0,  HH, true);
            frag[g * 2 + 1] = mk(Whh1, r0, HH, 32, HH, true);
        }
        const int rf = 16 * w + n;
        frag[8]  = mk(W1, rf, HH, 0,  HH, true);
        frag[9]  = mk(W1, rf, HH, 32, HH, true);
        bias[0] = bf1[rf];
        frag[10] = mk(W2, n, HH, 0,  HH, n < OO);
        frag[11] = mk(W2, n, HH, 32, HH, n < OO);
        bias[1] = (n < OO) ? bf2[n] : 0.f;
        #pragma unroll
        for (int i = 12; i < 20; ++i) frag[i] = frag[0];   // unused
    }

    // x is register-carried: opaque VGPR pointer forces vector (vmcnt) loads so
    // wave-uniform addresses cannot scalarize into lgkm-counted s_loads.
    const float* xrow = x + (size_t)row * TT * II;
    {
        unsigned long long p = (unsigned long long)xrow;
        asm volatile("" : "+v"(p));
        xrow = (const float*)p;
    }
    f32x4 xc03 = {0.f, 0.f, 0.f, 0.f};
    f32x2 xc45 = {0.f, 0.f};
    if (isA) {   // preload x[0]
        xc03 = *reinterpret_cast<const f32x4*>(xrow);
        xc45 = *reinterpret_cast<const f32x2*>(xrow + 4);
    }

    float* outrow = out + (size_t)row * TT * OO;
    float cst = 0.f;   // cell state: A lanes 0-15 hold c0[unit 16w+n]; B: c1

    __syncthreads();   // full barrier once, before the loop

    // slot parity (verified R6-R10): slp=(t+1)&1 holds {h0[t-1], h1[t-3], r[t-3]w},
    // slc=t&1 holds {h0[t]w, h1[t-2]w, xg1[t-2]r, r[t-4]r}
    for (int t = 0; t <= TT + 3; ++t) {
        const int slp = (t + 1) & 1;
        const int slc = t & 1;

        if (isA) {
            // issue x[t+1] prefetch FIRST: ~full iteration of latency cover
            const int tn = (t + 1 < TT) ? t + 1 : TT - 1;
            const float* xp = xrow + (size_t)tn * II;
            f32x4 xn03 = *reinterpret_cast<const f32x4*>(xp);
            f32x2 xn45 = *reinterpret_cast<const f32x2*>(xp + 4);

            // broadcast A-frags: every n-lane in a q-group reads the SAME 16B
            const f16x8 a0 = *reinterpret_cast<const f16x8*>(&H0[slp][8 * q]);
            const f16x8 a1 = *reinterpret_cast<const f16x8*>(&H0[slp][32 + 8 * q]);
            f16x8 a2;    // x[t] from regs; q>0 lanes hold junk (B-side is zero there)
            a2[0] = (_Float16)xc03[0]; a2[1] = (_Float16)xc03[1];
            a2[2] = (_Float16)xc03[2]; a2[3] = (_Float16)xc03[3];
            a2[4] = (_Float16)xc45[0]; a2[5] = (_Float16)xc45[1];
            a2[6] = (_Float16)0.f;     a2[7] = (_Float16)0.f;

            f32x4 d0, d1, d2, d3;
            #pragma unroll
            for (int g = 0; g < 4; ++g) {
                f32x4 acc = {bias[g], bias[g], bias[g], bias[g]};
                acc = MFMA(a0, frag[g * 3 + 0], acc);
                acc = MFMA(a1, frag[g * 3 + 1], acc);
                acc = MFMA(a2, frag[g * 3 + 2], acc);
                if (g == 0) d0 = acc; else if (g == 1) d1 = acc;
                else if (g == 2) d2 = acc; else d3 = acc;
                // G1b: xg1 = b1 + Wih1 . h0[t-1]  (same a0,a1 operands)
                f32x4 ae = {bias[4 + g], bias[4 + g], bias[4 + g], bias[4 + g]};
                ae = MFMA(a0, frag[12 + g * 2 + 0], ae);
                ae = MFMA(a1, frag[12 + g * 2 + 1], ae);
                if (lane < 16) XG[slp][16 * (4 * g + w) + lane] = ae[0];
            }
            if (t < TT) {
                float i_ = fast_sig(d0[0]), f_ = fast_sig(d1[0]);
                float g_ = fast_tanh(d2[0]), o_ = fast_sig(d3[0]);
                cst = f_ * cst + i_ * g_;
                float h = o_ * fast_tanh(cst);
                if (lane < 16) H0[slc][16 * w + lane] = (_Float16)h;
            }
            xc03 = xn03;   // vmcnt wait for these lands at a2-build next iter
            xc45 = xn45;
        } else {
            const int s2 = t - 2, s3 = t - 3, s4 = t - 4;
            const f16x8 a0 = *reinterpret_cast<const f16x8*>(&H1[slp][8 * q]);
            const f16x8 a1 = *reinterpret_cast<const f16x8*>(&H1[slp][32 + 8 * q]);
            f32x4 d0, d1, d2, d3;
            #pragma unroll
            for (int g = 0; g < 4; ++g) {
                const float xg = XG[slc][16 * (4 * g + w) + n];  // b1+Wih1.h0[s2]
                f32x4 acc = {xg, xg, xg, xg};
                acc = MFMA(a0, frag[g * 2 + 0], acc);
                acc = MFMA(a1, frag[g * 2 + 1], acc);
                if (g == 0) d0 = acc; else if (g == 1) d1 = acc;
                else if (g == 2) d2 = acc; else d3 = acc;
            }
            if (s2 >= 0 && s2 < TT) {
                float i_ = fast_sig(d0[0]), f_ = fast_sig(d1[0]);
                float g_ = fast_tanh(d2[0]), o_ = fast_sig(d3[0]);
                cst = f_ * cst + i_ * g_;
                float h = o_ * fast_tanh(cst);
                if (lane < 16) H1[slc][16 * w + lane] = (_Float16)h;
            }
            {   // FC1: relu(W1 . h1[s3] + bf1) -> Rb  (reuses a0,a1)
                f32x4 acc = {bias[0], bias[0], bias[0], bias[0]};
                acc = MFMA(a0, frag[8], acc);
                acc = MFMA(a1, frag[9], acc);
                if (s3 >= 0 && s3 < TT && lane < 16)
                    Rb[slp][16 * w + lane] = (_Float16)fmaxf(acc[0], 0.f);
            }
            if (w == 0) {   // FC2: W2 . r[s4] + bf2 -> out (store drains lazily)
                const f16x8 r0 = *reinterpret_cast<const f16x8*>(&Rb[slc][8 * q]);
                const f16x8 r1 = *reinterpret_cast<const f16x8*>(&Rb[slc][32 + 8 * q]);
                f32x4 acc = {bias[1], bias[1], bias[1], bias[1]};
                acc = MFMA(r0, frag[10], acc);
                acc = MFMA(r1, frag[11], acc);
                if (s4 >= 0 && s4 < TT && lane < OO)
                    outrow[(size_t)s4 * OO + lane] = acc[0];
            }
        }
        LGKM_BARRIER();   // LDS-only drain; global ops stay in flight
    }
}

extern "C" void kernel_launch(void* const* d_in, const int* in_sizes, int n_in,
                              void* d_out, int out_size, void* d_ws, size_t ws_size,
                              hipStream_t stream) {
    const float* xp   = (const float*)d_in[0];
    const float* Wih0 = (const float*)d_in[1];
    const float* Whh0 = (const float*)d_in[2];
    const float* b0   = (const float*)d_in[3];
    const float* Wih1 = (const float*)d_in[4];
    const float* Whh1 = (const float*)d_in[5];
    const float* b1   = (const float*)d_in[6];
    const float* W1   = (const float*)d_in[7];
    const float* bf1  = (const float*)d_in[8];
    const float* W2   = (const float*)d_in[9];
    const float* bf2  = (const float*)d_in[10];
    float* outp = (float*)d_out;

    lstm_mfma_kernel<<<dim3(256), dim3(NTHR), 0, stream>>>(
        xp, Wih0, Whh0, b0, Wih1, Whh1, b1, W1, bf1, W2, bf2, outp);
}